// Round 3
// baseline (165.664 us; speedup 1.0000x reference)
//
#include <hip/hip_runtime.h>
#include <cstdint>

// Jagged per-segment argmax — round 3.
// 16 lanes per segment, 4 segments per wave (mean segment length = 64).
//  - per-wave fixed cost amortized over 4 segments (256K waves vs 512K)
//  - reduction is row-local DPP (quad_perm xor1/xor2 + row_ror:4/8): never
//    leaves the 16-lane row, so NO readlane/cross-row combine at all
//  - value loads are unpredicated: divergent loop + exec mask does bounds
//  - group's 16 lanes load 64B contiguous -> coalesced; boundary loads are
//    same-address within a group -> HW broadcast
// Empty segments: all lanes stay (-inf, IMAX) -> out = IMAX (the
// jax segment_min int32 identity, verified in R0/R1).

#define IMAX 0x7FFFFFFF

// DPP ctrl: quad_perm(1,0,3,2)=0xB1 (xor1), quad_perm(2,3,0,1)=0x4E (xor2),
// row_ror:4=0x124, row_ror:8=0x128. All stay within the 16-lane row.
template<int CTRL>
__device__ __forceinline__ float dpp_fmax(float v) {
    int moved = __builtin_amdgcn_update_dpp((int)0xFF800000, __float_as_int(v),
                                            CTRL, 0xF, 0xF, false);
    return fmaxf(v, __int_as_float(moved));
}
template<int CTRL>
__device__ __forceinline__ int dpp_imin(int v) {
    int moved = __builtin_amdgcn_update_dpp(IMAX, v, CTRL, 0xF, 0xF, false);
    return min(v, moved);
}

__global__ __launch_bounds__(256) void jagged_argmax_kernel(
    const float* __restrict__ values,
    const int*   __restrict__ ps32,   // prefix_sum words (int32 or int64 LE)
    int n_seg,
    int* __restrict__ out)
{
    const int wave = blockIdx.x * (blockDim.x >> 6) + ((int)threadIdx.x >> 6);
    const int lane = (int)threadIdx.x & 63;
    const int g    = lane >> 4;          // segment-group 0..3 within wave
    const int l16  = lane & 15;
    const int seg0 = wave * 4;
    if (seg0 >= n_seg) return;           // wave-uniform exit
    const int seg  = seg0 + g;
    const int segc = min(seg, n_seg - 1);   // clamp for the tail wave

    // int64 LE => word1 = high word of ps[0] (< 2^31) == 0; int32 => ps[1] >= 1
    const bool is64 = (ps32[1] == 0);
    const long long* ps64 = (const long long*)ps32;

    int start, end;
    if (is64) {
        start = segc ? (int)ps64[segc - 1] : 0;
        end   = (int)ps64[segc];
    } else {
        start = segc ? ps32[segc - 1] : 0;
        end   = ps32[segc];
    }

    // Per-lane running (max, first-idx). Ascending i + strict '>' keeps the
    // first index per lane. Unpredicated loads; exec-mask handles bounds.
    float bv = __int_as_float(0xFF800000u);  // -inf
    int   bi = IMAX;
    for (int i = start + l16; i < end; i += 16) {
        float v = values[i];
        if (v > bv) { bv = v; bi = i; }
    }

    // Row-local 16-lane reduce: max value, then min index among maximal lanes.
    float m = bv;
    m = dpp_fmax<0xB1>(m);
    m = dpp_fmax<0x4E>(m);
    m = dpp_fmax<0x124>(m);
    m = dpp_fmax<0x128>(m);
    int cand = (bv == m) ? bi : IMAX;
    cand = dpp_imin<0xB1>(cand);
    cand = dpp_imin<0x4E>(cand);
    cand = dpp_imin<0x124>(cand);
    cand = dpp_imin<0x128>(cand);

    // lanes 0,16,32,48 write 4 consecutive dwords -> single-line store
    if (l16 == 0 && seg < n_seg) out[seg] = cand;
}

extern "C" void kernel_launch(void* const* d_in, const int* in_sizes, int n_in,
                              void* d_out, int out_size, void* d_ws, size_t ws_size,
                              hipStream_t stream) {
    const float* values = (const float*)d_in[0];
    const int*   ps32   = (const int*)d_in[1];
    const int n_seg = in_sizes[1];
    int* out = (int*)d_out;

    // 256 threads = 4 waves = 16 segments per block
    const int segs_per_block = 16;
    const int grid = (n_seg + segs_per_block - 1) / segs_per_block;
    jagged_argmax_kernel<<<grid, 256, 0, stream>>>(values, ps32, n_seg, out);
}

// Round 4
// 107.349 us; speedup vs baseline: 1.5432x; 1.5432x over previous
//
#include <hip/hip_runtime.h>
#include <cstdint>

// Jagged per-segment argmax — round 4: dense BW-bound segmented sweep.
//
// R2/R3 post-mortem: any per-segment decomposition is latency-bound (mean
// segment = 64 elements, ~900cy HBM chain per segment, HBM at 7-9% peak).
// R4 restructures: each block sweeps a contiguous 8192-element chunk of
// `values` with coalesced float4 loads (8 independent loads/lane, latency
// hidden by depth). Boundaries overlapping the chunk (~128 mean) staged in
// LDS; lanes walk a monotone boundary pointer (~1 cmp/element amortized).
// Partials combine via LDS atomicMax on packed u64:
//    key = (monotone_map(f32) << 32) | (0xFFFFFFFF - idx)
// => max value, ties -> MIN index (reference semantics). Interior segments
// stored directly; chunk-spanning segments atomicMax into ws (device scope,
// cross-XCD safe), resolved by a cleanup kernel. Empty segments (dup
// boundaries E) are owned by the chunk with E in (c0, c0+C] and get IMAX
// (the jax segment_min int32 identity, verified R0/R1).

#define IMAX      0x7FFFFFFF
#define C_CHUNK   8192
#define CAP       1024   // staged boundaries per chunk; mean ~128, P(overflow)~0
#define INIT_PACK 0x007FFFFF00000000ull   // pack(-inf, <none>)
#define NEG_INF   __int_as_float(0xFF800000u)

__device__ __forceinline__ unsigned long long pack_vi(float v, int idx) {
    unsigned u = __float_as_uint(v);
    u = (u & 0x80000000u) ? ~u : (u | 0x80000000u);   // monotone f32 -> u32
    return ((unsigned long long)u << 32) |
           (unsigned long long)(0xFFFFFFFFu - (unsigned)idx);
}
__device__ __forceinline__ int decode_idx(unsigned long long p) {
    if (p == INIT_PACK) return IMAX;
    return (int)(0xFFFFFFFFu - (unsigned)(p & 0xFFFFFFFFull));
}

__global__ void init_ws_kernel(unsigned long long* __restrict__ ws, int n_seg) {
    int i = blockIdx.x * blockDim.x + threadIdx.x;
    if (i < n_seg) ws[i] = INIT_PACK;
}

__global__ __launch_bounds__(256) void jagged_main_kernel(
    const float* __restrict__ values,
    const int*   __restrict__ ps32,   // prefix_sum words (int32 or int64 LE)
    int n_seg,
    int* __restrict__ out,
    unsigned long long* __restrict__ ws)
{
    __shared__ int lds_ps[CAP + 1];
    __shared__ unsigned long long lds_res[CAP];
    __shared__ int sh_s0, sh_start0;

    const int tid = (int)threadIdx.x;
    const int c0 = (int)blockIdx.x * C_CHUNK;
    const int chunkEnd = c0 + C_CHUNK;

    const bool is64 = (ps32[1] == 0);   // int64 LE: high word of ps[0] is 0
    const long long* ps64 = (const long long*)ps32;

    // ---- issue the chunk's value loads FIRST (independent of LDS work) ----
    const int w = tid >> 6, l = tid & 63;
    const int wavebase = c0 + w * (C_CHUNK / 4);      // 2048-elem wave quarter
    const float4* vp = (const float4*)(values + wavebase);  // 16B-aligned
    float4 d0 = vp[0*64 + l], d1 = vp[1*64 + l], d2 = vp[2*64 + l],
           d3 = vp[3*64 + l], d4 = vp[4*64 + l], d5 = vp[5*64 + l],
           d6 = vp[6*64 + l], d7 = vp[7*64 + l];

    // ---- s0 = first s with ps[s] > c0 (one binary search per block) ----
    if (tid == 0) {
        int lo = 0, hi = n_seg;
        while (lo < hi) {
            int mid = (lo + hi) >> 1;
            long long b = is64 ? ps64[mid] : (long long)ps32[mid];
            if (b > (long long)c0) hi = mid; else lo = mid + 1;
        }
        sh_s0 = lo;
        sh_start0 = lo ? (int)(is64 ? ps64[lo - 1] : (long long)ps32[lo - 1]) : 0;
    }
    __syncthreads();
    const int s0 = sh_s0;

    // ---- stage boundaries + init partial results ----
    for (int i = tid; i < CAP; i += 256) {
        int s = s0 + i;
        lds_ps[i] = (s < n_seg) ? (int)(is64 ? ps64[s] : (long long)ps32[s])
                                : IMAX;
        lds_res[i] = INIT_PACK;
    }
    if (tid == 0) lds_ps[CAP] = IMAX;    // hard stop: walk can never hang
    __syncthreads();

    // ---- per-lane boundary pointer: first slot with lds_ps[j] > firstidx ----
    const int firstidx = wavebase + l * 4;
    int lo = 0, hi = CAP;
    while (lo < hi) {
        int mid = (lo + hi) >> 1;
        if (lds_ps[mid] > firstidx) hi = mid; else lo = mid + 1;
    }
    int j = lo;
    int bnd = lds_ps[j];
    float bv = NEG_INF;
    int   bi = IMAX;

    // ---- process 8 clumps x 4 elements; lanes interleaved (coalesced) ----
#define PROC_ELEM(VV, E)                                             \
    {                                                                \
        int idx = base + (E);                                        \
        float v = (VV);                                              \
        while (idx >= bnd) {                                         \
            if (bi != IMAX)                                          \
                atomicMax(&lds_res[min(j, CAP - 1)], pack_vi(bv, bi)); \
            bv = NEG_INF; bi = IMAX;                                 \
            ++j; bnd = lds_ps[min(j, CAP)];                          \
        }                                                            \
        if (v > bv) { bv = v; bi = idx; }                            \
    }
#define PROC_CLUMP(K, D)                                             \
    {                                                                \
        int base = wavebase + (K) * 256 + l * 4;                     \
        PROC_ELEM((D).x, 0) PROC_ELEM((D).y, 1)                      \
        PROC_ELEM((D).z, 2) PROC_ELEM((D).w, 3)                      \
    }
    PROC_CLUMP(0, d0) PROC_CLUMP(1, d1) PROC_CLUMP(2, d2) PROC_CLUMP(3, d3)
    PROC_CLUMP(4, d4) PROC_CLUMP(5, d5) PROC_CLUMP(6, d6) PROC_CLUMP(7, d7)
#undef PROC_CLUMP
#undef PROC_ELEM
    if (bi != IMAX) atomicMax(&lds_res[min(j, CAP - 1)], pack_vi(bv, bi));
    __syncthreads();

    // ---- writeback: exactly one owner per segment writes `out` ----
    const int start0 = sh_start0;
    for (int ls = tid; ls < CAP; ls += 256) {
        int s = s0 + ls;
        if (s >= n_seg) break;
        int end_b   = lds_ps[ls];
        int start_b = ls ? lds_ps[ls - 1] : start0;
        if (start_b == end_b) {
            // empty segment: owned by the chunk with boundary in (c0, chunkEnd]
            if (start_b > c0 && start_b <= chunkEnd) out[s] = IMAX;
        } else if (start_b < chunkEnd && end_b > c0) {       // touches chunk
            if (start_b >= c0 && end_b <= chunkEnd)          // interior: final
                out[s] = decode_idx(lds_res[ls]);
            else                                             // spans chunks
                atomicMax(&ws[s], lds_res[ls]);
        }
    }
}

__global__ void resolve_edges_kernel(
    const int* __restrict__ ps32, int n_seg,
    const unsigned long long* __restrict__ ws,
    int* __restrict__ out)
{
    int s = blockIdx.x * blockDim.x + threadIdx.x;
    if (s >= n_seg) return;
    const bool is64 = (ps32[1] == 0);
    const long long* ps64 = (const long long*)ps32;
    int end   = (int)(is64 ? ps64[s] : (long long)ps32[s]);
    int start = s ? (int)(is64 ? ps64[s - 1] : (long long)ps32[s - 1]) : 0;
    if (start < end && (start / C_CHUNK) != ((end - 1) / C_CHUNK))
        out[s] = decode_idx(ws[s]);
}

// ---------------- fallback (R2 kernel) if ws is too small ----------------
template<int CTRL>
__device__ __forceinline__ float dpp_fmax(float v) {
    int moved = __builtin_amdgcn_update_dpp((int)0xFF800000, __float_as_int(v),
                                            CTRL, 0xF, 0xF, false);
    return fmaxf(v, __int_as_float(moved));
}
template<int CTRL>
__device__ __forceinline__ int dpp_imin(int v) {
    int moved = __builtin_amdgcn_update_dpp(IMAX, v, CTRL, 0xF, 0xF, false);
    return min(v, moved);
}
__device__ __forceinline__ int wave_argmax64(float bv, int bi) {
    float m = bv;
    m = dpp_fmax<0xB1>(m); m = dpp_fmax<0x4E>(m);
    m = dpp_fmax<0x124>(m); m = dpp_fmax<0x128>(m);
    float r0 = __int_as_float(__builtin_amdgcn_readlane(__float_as_int(m), 0));
    float r1 = __int_as_float(__builtin_amdgcn_readlane(__float_as_int(m), 16));
    float r2 = __int_as_float(__builtin_amdgcn_readlane(__float_as_int(m), 32));
    float r3 = __int_as_float(__builtin_amdgcn_readlane(__float_as_int(m), 48));
    float maxv = fmaxf(fmaxf(r0, r1), fmaxf(r2, r3));
    int cand = (bv == maxv) ? bi : IMAX;
    cand = dpp_imin<0xB1>(cand); cand = dpp_imin<0x4E>(cand);
    cand = dpp_imin<0x124>(cand); cand = dpp_imin<0x128>(cand);
    int i0 = __builtin_amdgcn_readlane(cand, 0);
    int i1 = __builtin_amdgcn_readlane(cand, 16);
    int i2 = __builtin_amdgcn_readlane(cand, 32);
    int i3 = __builtin_amdgcn_readlane(cand, 48);
    return min(min(i0, i1), min(i2, i3));
}
__device__ __forceinline__ void upd_pair(const float* __restrict__ values,
                                         int i, int end, float& bv, int& bi) {
    float v0 = (i     < end) ? values[i]     : NEG_INF;
    float v1 = (i + 1 < end) ? values[i + 1] : NEG_INF;
    if (v0 > bv) { bv = v0; bi = i; }
    if (v1 > bv) { bv = v1; bi = i + 1; }
}
__global__ __launch_bounds__(256) void jagged_fallback_kernel(
    const float* __restrict__ values, const int* __restrict__ ps32,
    int n_seg, int* __restrict__ out)
{
    const int pair = blockIdx.x * (blockDim.x >> 6) + ((int)threadIdx.x >> 6);
    const int lane = (int)threadIdx.x & 63;
    const int seg0 = pair * 2;
    if (seg0 >= n_seg) return;
    const bool has1 = (seg0 + 1) < n_seg;
    const bool is64 = (ps32[1] == 0);
    const long long* ps64 = (const long long*)ps32;
    int s0, e0, e1;
    if (is64) { s0 = seg0 ? (int)ps64[seg0-1] : 0; e0 = (int)ps64[seg0];
                e1 = has1 ? (int)ps64[seg0+1] : e0; }
    else      { s0 = seg0 ? ps32[seg0-1] : 0; e0 = ps32[seg0];
                e1 = has1 ? ps32[seg0+1] : e0; }
    float bv0 = NEG_INF, bv1 = NEG_INF; int bi0 = IMAX, bi1 = IMAX;
    upd_pair(values, s0 + 2*lane, e0, bv0, bi0);
    upd_pair(values, e0 + 2*lane, e1, bv1, bi1);
    for (int i = s0 + 2*lane + 128; i < e0; i += 128) upd_pair(values, i, e0, bv0, bi0);
    for (int i = e0 + 2*lane + 128; i < e1; i += 128) upd_pair(values, i, e1, bv1, bi1);
    int idx0 = wave_argmax64(bv0, bi0);
    int idx1 = wave_argmax64(bv1, bi1);
    int myi = (lane == 0) ? idx0 : idx1;
    if (lane < (has1 ? 2 : 1)) out[seg0 + lane] = myi;
}

extern "C" void kernel_launch(void* const* d_in, const int* in_sizes, int n_in,
                              void* d_out, int out_size, void* d_ws, size_t ws_size,
                              hipStream_t stream) {
    const float* values = (const float*)d_in[0];
    const int*   ps32   = (const int*)d_in[1];
    const int n_seg = in_sizes[1];
    const int total = in_sizes[0];
    int* out = (int*)d_out;

    if (ws_size >= (size_t)n_seg * 8 && (total % C_CHUNK) == 0) {
        unsigned long long* ws = (unsigned long long*)d_ws;
        init_ws_kernel<<<(n_seg + 255) / 256, 256, 0, stream>>>(ws, n_seg);
        jagged_main_kernel<<<total / C_CHUNK, 256, 0, stream>>>(
            values, ps32, n_seg, out, ws);
        resolve_edges_kernel<<<(n_seg + 255) / 256, 256, 0, stream>>>(
            ps32, n_seg, ws, out);
    } else {
        const int segs_per_block = 8;
        const int grid = (n_seg + segs_per_block - 1) / segs_per_block;
        jagged_fallback_kernel<<<grid, 256, 0, stream>>>(values, ps32, n_seg, out);
    }
}

// Round 5
// 85.021 us; speedup vs baseline: 1.9485x; 1.2626x over previous
//
#include <hip/hip_runtime.h>
#include <cstdint>

// Jagged per-segment argmax — round 5: dense sweep, transposed lanes, 1+1 kernels.
//
// R4 post-mortem: interleaved clumps made each 64-elem segment touch ~17
// lanes -> ~17.8M u64 LDS atomics w/ heavy same-address serialization; tid0's
// binary search was a ~6000cy serial block prologue; init/resolve kernels
// added ~15-20us. R5:
//  - chunk_starts kernel precomputes (s0, start0) per chunk into ws
//  - main kernel: coalesced float4 loads -> per-wave XOR-swizzled LDS
//    transpose (conflict-free, barrier-free: wave-private 8KB) -> each lane
//    owns 32 CONTIGUOUS elements -> segment touches ~3 lanes -> ~3M atomics
//  - chunk-spanning segments (<=1 owned per chunk) rescanned from global by
//    wave 0 of the owner block; no ws partials, no resolve kernel
// Empty segments (dup boundary E): owned by chunk with E in (c0, chunkEnd],
// output IMAX (jax segment_min int32 identity, verified R0/R1).

#define IMAX      0x7FFFFFFF
#define C_CHUNK   8192
#define CAP       512    // staged boundaries/chunk; mean 125, max~180 -> huge margin
#define INIT_PACK 0x007FFFFF00000000ull   // pack(-inf, none)
#define NEG_INF   __int_as_float(0xFF800000u)

__device__ __forceinline__ unsigned long long pack_vi(float v, int idx) {
    unsigned u = __float_as_uint(v);
    u = (u & 0x80000000u) ? ~u : (u | 0x80000000u);   // monotone f32 -> u32
    return ((unsigned long long)u << 32) |
           (unsigned long long)(0xFFFFFFFFu - (unsigned)idx);
}
__device__ __forceinline__ int decode_idx(unsigned long long p) {
    if (p == INIT_PACK) return IMAX;
    return (int)(0xFFFFFFFFu - (unsigned)(p & 0xFFFFFFFFull));
}

// ---- 64-lane DPP argmax (max value, ties -> min index), from R2 ----
template<int CTRL>
__device__ __forceinline__ float dpp_fmax(float v) {
    int moved = __builtin_amdgcn_update_dpp((int)0xFF800000, __float_as_int(v),
                                            CTRL, 0xF, 0xF, false);
    return fmaxf(v, __int_as_float(moved));
}
template<int CTRL>
__device__ __forceinline__ int dpp_imin(int v) {
    int moved = __builtin_amdgcn_update_dpp(IMAX, v, CTRL, 0xF, 0xF, false);
    return min(v, moved);
}
__device__ __forceinline__ int wave_argmax64(float bv, int bi) {
    float m = bv;
    m = dpp_fmax<0xB1>(m); m = dpp_fmax<0x4E>(m);
    m = dpp_fmax<0x124>(m); m = dpp_fmax<0x128>(m);
    float r0 = __int_as_float(__builtin_amdgcn_readlane(__float_as_int(m), 0));
    float r1 = __int_as_float(__builtin_amdgcn_readlane(__float_as_int(m), 16));
    float r2 = __int_as_float(__builtin_amdgcn_readlane(__float_as_int(m), 32));
    float r3 = __int_as_float(__builtin_amdgcn_readlane(__float_as_int(m), 48));
    float maxv = fmaxf(fmaxf(r0, r1), fmaxf(r2, r3));
    int cand = (bv == maxv) ? bi : IMAX;
    cand = dpp_imin<0xB1>(cand); cand = dpp_imin<0x4E>(cand);
    cand = dpp_imin<0x124>(cand); cand = dpp_imin<0x128>(cand);
    int i0 = __builtin_amdgcn_readlane(cand, 0);
    int i1 = __builtin_amdgcn_readlane(cand, 16);
    int i2 = __builtin_amdgcn_readlane(cand, 32);
    int i3 = __builtin_amdgcn_readlane(cand, 48);
    return min(min(i0, i1), min(i2, i3));
}

// ---- kernel 1: per-chunk (s0 = first seg with end > c0, start0 = its start) ----
__global__ void chunk_starts_kernel(const int* __restrict__ ps32, int n_seg,
                                    int nchunks, int2* __restrict__ cs) {
    int c = blockIdx.x * blockDim.x + threadIdx.x;
    if (c >= nchunks) return;
    const bool is64 = (ps32[1] == 0);
    const long long* ps64 = (const long long*)ps32;
    long long c0 = (long long)c * C_CHUNK;
    int lo = 0, hi = n_seg;
    while (lo < hi) {
        int mid = (lo + hi) >> 1;
        long long b = is64 ? ps64[mid] : (long long)ps32[mid];
        if (b > c0) hi = mid; else lo = mid + 1;
    }
    int start0 = lo ? (int)(is64 ? ps64[lo - 1] : (long long)ps32[lo - 1]) : 0;
    cs[c] = make_int2(lo, start0);
}

// ---- kernel 2: main sweep ----
__global__ __launch_bounds__(256) void jagged_main_kernel(
    const float* __restrict__ values,
    const int*   __restrict__ ps32,
    int n_seg,
    int* __restrict__ out,
    const int2* __restrict__ cs)
{
    __shared__ int lds_ps[CAP + 1];
    __shared__ unsigned long long lds_res[CAP];
    __shared__ float4 lds_tr[4 * 512];     // 32KB: per-wave 8KB transpose buffer
    __shared__ int sh_span;

    const int tid = (int)threadIdx.x;
    const int c0 = (int)blockIdx.x * C_CHUNK;
    const int chunkEnd = c0 + C_CHUNK;
    const int w = tid >> 6, l = tid & 63;

    // issue the wave-quarter's 8 coalesced float4 loads first
    const int wavebase = c0 + w * 2048;
    const float4* vp = (const float4*)(values + wavebase);
    float4 d0 = vp[0*64 + l], d1 = vp[1*64 + l], d2 = vp[2*64 + l],
           d3 = vp[3*64 + l], d4 = vp[4*64 + l], d5 = vp[5*64 + l],
           d6 = vp[6*64 + l], d7 = vp[7*64 + l];

    const int2 sw = cs[blockIdx.x];
    const int s0 = sw.x, start0 = sw.y;

    const bool is64 = (ps32[1] == 0);
    const long long* ps64 = (const long long*)ps32;

    for (int i = tid; i < CAP; i += 256) {
        int s = s0 + i;
        lds_ps[i] = (s < n_seg) ? (int)(is64 ? ps64[s] : (long long)ps32[s])
                                : IMAX;
        lds_res[i] = INIT_PACK;
    }
    if (tid == 0) { lds_ps[CAP] = IMAX; sh_span = -1; }
    __syncthreads();

    // ---- wave-private XOR-swizzled transpose: lane gets 32 CONTIGUOUS elems.
    // logical granule g (16B) stored at phys p = g ^ ((g>>6)&7); both the
    // write pattern (g=k*64+l) and read pattern (g=l*8+r) hit each bank-group
    // uniformly 8x = the b128 throughput floor. No barrier: wave-private
    // region; compiler's lgkmcnt covers write->read ordering in-wave.
    float4* tr = lds_tr + w * 512;
    tr[(0*64 + l) ^ 0] = d0;  tr[(1*64 + l) ^ 1] = d1;
    tr[(2*64 + l) ^ 2] = d2;  tr[(3*64 + l) ^ 3] = d3;
    tr[(4*64 + l) ^ 4] = d4;  tr[(5*64 + l) ^ 5] = d5;
    tr[(6*64 + l) ^ 6] = d6;  tr[(7*64 + l) ^ 7] = d7;
    const int lhi = l >> 3;
    float4 e0 = tr[(l*8 + 0) ^ lhi], e1 = tr[(l*8 + 1) ^ lhi],
           e2 = tr[(l*8 + 2) ^ lhi], e3 = tr[(l*8 + 3) ^ lhi],
           e4 = tr[(l*8 + 4) ^ lhi], e5 = tr[(l*8 + 5) ^ lhi],
           e6 = tr[(l*8 + 6) ^ lhi], e7 = tr[(l*8 + 7) ^ lhi];

    // ---- boundary pointer for this lane's contiguous run [mybase, +32) ----
    const int mybase = wavebase + l * 32;
    int lo = 0, hi = CAP;
    while (lo < hi) {
        int mid = (lo + hi) >> 1;
        if (lds_ps[mid] > mybase) hi = mid; else lo = mid + 1;
    }
    int j = lo;
    int bnd = lds_ps[j];
    float bv = NEG_INF;
    int   bi = IMAX;

#define PROC_ELEM(VV, OFF)                                              \
    {                                                                   \
        int idx = mybase + (OFF);                                       \
        float v = (VV);                                                 \
        while (idx >= bnd) {                                            \
            if (bi != IMAX)                                             \
                atomicMax(&lds_res[min(j, CAP - 1)], pack_vi(bv, bi));  \
            bv = NEG_INF; bi = IMAX;                                    \
            ++j; bnd = lds_ps[min(j, CAP)];                             \
        }                                                               \
        if (v > bv) { bv = v; bi = idx; }                               \
    }
#define PROC4(R, E)                                                     \
    PROC_ELEM((E).x, (R)*4 + 0) PROC_ELEM((E).y, (R)*4 + 1)             \
    PROC_ELEM((E).z, (R)*4 + 2) PROC_ELEM((E).w, (R)*4 + 3)
    PROC4(0, e0) PROC4(1, e1) PROC4(2, e2) PROC4(3, e3)
    PROC4(4, e4) PROC4(5, e5) PROC4(6, e6) PROC4(7, e7)
#undef PROC4
#undef PROC_ELEM
    if (bi != IMAX) atomicMax(&lds_res[min(j, CAP - 1)], pack_vi(bv, bi));
    __syncthreads();

    // ---- writeback: one owner per segment ----
    for (int ls = tid; ls < CAP; ls += 256) {
        int s = s0 + ls;
        if (s >= n_seg) break;
        int end_b   = lds_ps[ls];
        int start_b = ls ? lds_ps[ls - 1] : start0;
        if (start_b == end_b) {
            if (start_b > c0 && start_b <= chunkEnd) out[s] = IMAX;  // empty
        } else if (start_b >= c0 && start_b < chunkEnd) {            // starts here
            if (end_b <= chunkEnd) out[s] = decode_idx(lds_res[ls]); // interior
            else sh_span = ls;            // spans right edge: <=1 per chunk
        }
        // start_b < c0: owned (rescanned) by an earlier chunk
    }
    __syncthreads();

    // ---- wave 0 rescans the (rare) owned spanning segment from global ----
    const int span = sh_span;
    if (span >= 0 && w == 0) {
        int end_b   = lds_ps[span];
        int start_b = span ? lds_ps[span - 1] : start0;
        float sv = NEG_INF; int si = IMAX;
        for (int i = start_b + l; i < end_b; i += 64) {
            float v = values[i];
            if (v > sv) { sv = v; si = i; }
        }
        int idx = wave_argmax64(sv, si);
        if (l == 0) out[s0 + span] = idx;
    }
}

// ---------------- fallback (R2 kernel) ----------------
__device__ __forceinline__ void upd_pair(const float* __restrict__ values,
                                         int i, int end, float& bv, int& bi) {
    float v0 = (i     < end) ? values[i]     : NEG_INF;
    float v1 = (i + 1 < end) ? values[i + 1] : NEG_INF;
    if (v0 > bv) { bv = v0; bi = i; }
    if (v1 > bv) { bv = v1; bi = i + 1; }
}
__global__ __launch_bounds__(256) void jagged_fallback_kernel(
    const float* __restrict__ values, const int* __restrict__ ps32,
    int n_seg, int* __restrict__ out)
{
    const int pair = blockIdx.x * (blockDim.x >> 6) + ((int)threadIdx.x >> 6);
    const int lane = (int)threadIdx.x & 63;
    const int seg0 = pair * 2;
    if (seg0 >= n_seg) return;
    const bool has1 = (seg0 + 1) < n_seg;
    const bool is64 = (ps32[1] == 0);
    const long long* ps64 = (const long long*)ps32;
    int s0, e0, e1;
    if (is64) { s0 = seg0 ? (int)ps64[seg0-1] : 0; e0 = (int)ps64[seg0];
                e1 = has1 ? (int)ps64[seg0+1] : e0; }
    else      { s0 = seg0 ? ps32[seg0-1] : 0; e0 = ps32[seg0];
                e1 = has1 ? ps32[seg0+1] : e0; }
    float bv0 = NEG_INF, bv1 = NEG_INF; int bi0 = IMAX, bi1 = IMAX;
    upd_pair(values, s0 + 2*lane, e0, bv0, bi0);
    upd_pair(values, e0 + 2*lane, e1, bv1, bi1);
    for (int i = s0 + 2*lane + 128; i < e0; i += 128) upd_pair(values, i, e0, bv0, bi0);
    for (int i = e0 + 2*lane + 128; i < e1; i += 128) upd_pair(values, i, e1, bv1, bi1);
    int idx0 = wave_argmax64(bv0, bi0);
    int idx1 = wave_argmax64(bv1, bi1);
    int myi = (lane == 0) ? idx0 : idx1;
    if (lane < (has1 ? 2 : 1)) out[seg0 + lane] = myi;
}

extern "C" void kernel_launch(void* const* d_in, const int* in_sizes, int n_in,
                              void* d_out, int out_size, void* d_ws, size_t ws_size,
                              hipStream_t stream) {
    const float* values = (const float*)d_in[0];
    const int*   ps32   = (const int*)d_in[1];
    const int n_seg = in_sizes[1];
    const int total = in_sizes[0];
    int* out = (int*)d_out;

    const int nchunks = total / C_CHUNK;
    if ((total % C_CHUNK) == 0 && ws_size >= (size_t)nchunks * sizeof(int2)) {
        int2* cs = (int2*)d_ws;
        chunk_starts_kernel<<<(nchunks + 255) / 256, 256, 0, stream>>>(
            ps32, n_seg, nchunks, cs);
        jagged_main_kernel<<<nchunks, 256, 0, stream>>>(
            values, ps32, n_seg, out, cs);
    } else {
        const int segs_per_block = 8;
        const int grid = (n_seg + segs_per_block - 1) / segs_per_block;
        jagged_fallback_kernel<<<grid, 256, 0, stream>>>(values, ps32, n_seg, out);
    }
}

// Round 6
// 61.407 us; speedup vs baseline: 2.6978x; 1.3845x over previous
//
#include <hip/hip_runtime.h>
#include <cstdint>

// Jagged per-segment argmax — round 6: no-LDS-transpose dense sweep.
//
// R5 post-mortem: 32KB lds_tr capped occupancy at 4 blocks/CU and forced a
// full vmcnt(0) drain before compute; transpose cost 16 DS b128/wave. R6:
//  - lane owns 16 CONTIGUOUS elements, loaded DIRECTLY as 4 float4 at
//    64B lane stride: all 4 instrs touch the same 32 lines -> MSHR/L1 reuse,
//    same HBM bytes, zero LDS transpose, no full drain
//  - C_CHUNK=4096 (256 threads x 16) so each lane has ONE run (no j jumps)
//  - LDS ~3.8KB -> 8 blocks/CU (32 waves/CU), 2x R5 occupancy
//  - chunk_starts kernel precomputes (s0, start0) per chunk into ws
//  - segment results merge via LDS atomicMax on packed u64
//    (monotone f32 <<32 | ~idx) = max value, ties -> min index
//  - right-edge-spanning segment (<=1 per chunk) rescanned from global
//    (L2-warm) by wave 0 of the owner block
// Empty segments (dup boundary E): owned by chunk with E in (c0, chunkEnd],
// output IMAX (jax segment_min int32 identity, verified R0/R1).

#define IMAX      0x7FFFFFFF
#define C_CHUNK   4096
#define CAP       240    // boundaries/chunk: mean 63, sigma 8 -> 22-sigma margin
#define INIT_PACK 0x007FFFFF00000000ull   // pack(-inf, none)
#define NEG_INF   __int_as_float(0xFF800000u)

__device__ __forceinline__ unsigned long long pack_vi(float v, int idx) {
    unsigned u = __float_as_uint(v);
    u = (u & 0x80000000u) ? ~u : (u | 0x80000000u);   // monotone f32 -> u32
    return ((unsigned long long)u << 32) |
           (unsigned long long)(0xFFFFFFFFu - (unsigned)idx);
}
__device__ __forceinline__ int decode_idx(unsigned long long p) {
    if (p == INIT_PACK) return IMAX;
    return (int)(0xFFFFFFFFu - (unsigned)(p & 0xFFFFFFFFull));
}

// ---- 64-lane DPP argmax (max value, ties -> min index) ----
template<int CTRL>
__device__ __forceinline__ float dpp_fmax(float v) {
    int moved = __builtin_amdgcn_update_dpp((int)0xFF800000, __float_as_int(v),
                                            CTRL, 0xF, 0xF, false);
    return fmaxf(v, __int_as_float(moved));
}
template<int CTRL>
__device__ __forceinline__ int dpp_imin(int v) {
    int moved = __builtin_amdgcn_update_dpp(IMAX, v, CTRL, 0xF, 0xF, false);
    return min(v, moved);
}
__device__ __forceinline__ int wave_argmax64(float bv, int bi) {
    float m = bv;
    m = dpp_fmax<0xB1>(m); m = dpp_fmax<0x4E>(m);
    m = dpp_fmax<0x124>(m); m = dpp_fmax<0x128>(m);
    float r0 = __int_as_float(__builtin_amdgcn_readlane(__float_as_int(m), 0));
    float r1 = __int_as_float(__builtin_amdgcn_readlane(__float_as_int(m), 16));
    float r2 = __int_as_float(__builtin_amdgcn_readlane(__float_as_int(m), 32));
    float r3 = __int_as_float(__builtin_amdgcn_readlane(__float_as_int(m), 48));
    float maxv = fmaxf(fmaxf(r0, r1), fmaxf(r2, r3));
    int cand = (bv == maxv) ? bi : IMAX;
    cand = dpp_imin<0xB1>(cand); cand = dpp_imin<0x4E>(cand);
    cand = dpp_imin<0x124>(cand); cand = dpp_imin<0x128>(cand);
    int i0 = __builtin_amdgcn_readlane(cand, 0);
    int i1 = __builtin_amdgcn_readlane(cand, 16);
    int i2 = __builtin_amdgcn_readlane(cand, 32);
    int i3 = __builtin_amdgcn_readlane(cand, 48);
    return min(min(i0, i1), min(i2, i3));
}

// ---- kernel 1: per-chunk (s0 = first seg with end > c0, start0 = its start) ----
__global__ void chunk_starts_kernel(const int* __restrict__ ps32, int n_seg,
                                    int nchunks, int2* __restrict__ cs) {
    int c = blockIdx.x * blockDim.x + threadIdx.x;
    if (c >= nchunks) return;
    const bool is64 = (ps32[1] == 0);
    const long long* ps64 = (const long long*)ps32;
    long long c0 = (long long)c * C_CHUNK;
    int lo = 0, hi = n_seg;
    while (lo < hi) {
        int mid = (lo + hi) >> 1;
        long long b = is64 ? ps64[mid] : (long long)ps32[mid];
        if (b > c0) hi = mid; else lo = mid + 1;
    }
    int start0 = lo ? (int)(is64 ? ps64[lo - 1] : (long long)ps32[lo - 1]) : 0;
    cs[c] = make_int2(lo, start0);
}

// ---- kernel 2: main sweep ----
__global__ __launch_bounds__(256) void jagged_main_kernel(
    const float* __restrict__ values,
    const int*   __restrict__ ps32,
    int n_seg,
    int* __restrict__ out,
    const int2* __restrict__ cs)
{
    __shared__ int lds_ps[CAP + 1];
    __shared__ unsigned long long lds_res[CAP];
    __shared__ int sh_span;

    const int tid = (int)threadIdx.x;
    const int c0 = (int)blockIdx.x * C_CHUNK;
    const int chunkEnd = c0 + C_CHUNK;
    const int w = tid >> 6, l = tid & 63;

    // lane's 16 contiguous elements: 4 float4 loads, 64B lane stride.
    // All 4 instrs touch the same 32 cache lines -> L1/MSHR reuse.
    const int mybase = c0 + (tid << 4);               // w*1024 + l*16
    const float4* vp = (const float4*)(values + mybase);
    float4 e0 = vp[0], e1 = vp[1], e2 = vp[2], e3 = vp[3];

    const int2 sw = cs[blockIdx.x];
    const int s0 = sw.x, start0 = sw.y;

    const bool is64 = (ps32[1] == 0);
    const long long* ps64 = (const long long*)ps32;

    if (tid < CAP) {
        int s = s0 + tid;
        lds_ps[tid] = (s < n_seg) ? (int)(is64 ? ps64[s] : (long long)ps32[s])
                                  : IMAX;
        lds_res[tid] = INIT_PACK;
    }
    if (tid == 0) { lds_ps[CAP] = IMAX; sh_span = -1; }
    __syncthreads();

    // ---- boundary pointer for this lane's run [mybase, mybase+16) ----
    int lo = 0, hi = CAP;
    while (lo < hi) {
        int mid = (lo + hi) >> 1;
        if (lds_ps[mid] > mybase) hi = mid; else lo = mid + 1;
    }
    int j = lo;
    int bnd = lds_ps[j];
    float bv = NEG_INF;
    int   bi = IMAX;

#define PROC_ELEM(VV, OFF)                                              \
    {                                                                   \
        int idx = mybase + (OFF);                                       \
        float v = (VV);                                                 \
        while (idx >= bnd) {                                            \
            if (bi != IMAX)                                             \
                atomicMax(&lds_res[min(j, CAP - 1)], pack_vi(bv, bi));  \
            bv = NEG_INF; bi = IMAX;                                    \
            ++j; bnd = lds_ps[min(j, CAP)];                             \
        }                                                               \
        if (v > bv) { bv = v; bi = idx; }                               \
    }
#define PROC4(R, E)                                                     \
    PROC_ELEM((E).x, (R)*4 + 0) PROC_ELEM((E).y, (R)*4 + 1)             \
    PROC_ELEM((E).z, (R)*4 + 2) PROC_ELEM((E).w, (R)*4 + 3)
    PROC4(0, e0) PROC4(1, e1) PROC4(2, e2) PROC4(3, e3)
#undef PROC4
#undef PROC_ELEM
    if (bi != IMAX) atomicMax(&lds_res[min(j, CAP - 1)], pack_vi(bv, bi));
    __syncthreads();

    // ---- writeback: one owner per segment ----
    if (tid < CAP) {
        int s = s0 + tid;
        if (s < n_seg) {
            int end_b   = lds_ps[tid];
            int start_b = tid ? lds_ps[tid - 1] : start0;
            if (start_b == end_b) {
                if (start_b > c0 && start_b <= chunkEnd) out[s] = IMAX; // empty
            } else if (start_b >= c0 && start_b < chunkEnd) {          // starts here
                if (end_b <= chunkEnd) out[s] = decode_idx(lds_res[tid]);
                else sh_span = tid;        // spans right edge: <=1 per chunk
            }
            // start_b < c0: owned (rescanned) by an earlier chunk
        }
    }
    __syncthreads();

    // ---- wave 0 rescans the owned right-spanning segment from global ----
    const int span = sh_span;
    if (span >= 0 && w == 0) {
        int end_b   = lds_ps[span];
        int start_b = span ? lds_ps[span - 1] : start0;
        float sv = NEG_INF; int si = IMAX;
        for (int i = start_b + l; i < end_b; i += 64) {
            float v = values[i];
            if (v > sv) { sv = v; si = i; }
        }
        int idx = wave_argmax64(sv, si);
        if (l == 0) out[s0 + span] = idx;
    }
}

// ---------------- fallback (R2 kernel) ----------------
__device__ __forceinline__ void upd_pair(const float* __restrict__ values,
                                         int i, int end, float& bv, int& bi) {
    float v0 = (i     < end) ? values[i]     : NEG_INF;
    float v1 = (i + 1 < end) ? values[i + 1] : NEG_INF;
    if (v0 > bv) { bv = v0; bi = i; }
    if (v1 > bv) { bv = v1; bi = i + 1; }
}
__global__ __launch_bounds__(256) void jagged_fallback_kernel(
    const float* __restrict__ values, const int* __restrict__ ps32,
    int n_seg, int* __restrict__ out)
{
    const int pair = blockIdx.x * (blockDim.x >> 6) + ((int)threadIdx.x >> 6);
    const int lane = (int)threadIdx.x & 63;
    const int seg0 = pair * 2;
    if (seg0 >= n_seg) return;
    const bool has1 = (seg0 + 1) < n_seg;
    const bool is64 = (ps32[1] == 0);
    const long long* ps64 = (const long long*)ps32;
    int s0, e0, e1;
    if (is64) { s0 = seg0 ? (int)ps64[seg0-1] : 0; e0 = (int)ps64[seg0];
                e1 = has1 ? (int)ps64[seg0+1] : e0; }
    else      { s0 = seg0 ? ps32[seg0-1] : 0; e0 = ps32[seg0];
                e1 = has1 ? ps32[seg0+1] : e0; }
    float bv0 = NEG_INF, bv1 = NEG_INF; int bi0 = IMAX, bi1 = IMAX;
    upd_pair(values, s0 + 2*lane, e0, bv0, bi0);
    upd_pair(values, e0 + 2*lane, e1, bv1, bi1);
    for (int i = s0 + 2*lane + 128; i < e0; i += 128) upd_pair(values, i, e0, bv0, bi0);
    for (int i = e0 + 2*lane + 128; i < e1; i += 128) upd_pair(values, i, e1, bv1, bi1);
    int idx0 = wave_argmax64(bv0, bi0);
    int idx1 = wave_argmax64(bv1, bi1);
    int myi = (lane == 0) ? idx0 : idx1;
    if (lane < (has1 ? 2 : 1)) out[seg0 + lane] = myi;
}

extern "C" void kernel_launch(void* const* d_in, const int* in_sizes, int n_in,
                              void* d_out, int out_size, void* d_ws, size_t ws_size,
                              hipStream_t stream) {
    const float* values = (const float*)d_in[0];
    const int*   ps32   = (const int*)d_in[1];
    const int n_seg = in_sizes[1];
    const int total = in_sizes[0];
    int* out = (int*)d_out;

    const int nchunks = total / C_CHUNK;
    if ((total % C_CHUNK) == 0 && ws_size >= (size_t)nchunks * sizeof(int2)) {
        int2* cs = (int2*)d_ws;
        chunk_starts_kernel<<<(nchunks + 255) / 256, 256, 0, stream>>>(
            ps32, n_seg, nchunks, cs);
        jagged_main_kernel<<<nchunks, 256, 0, stream>>>(
            values, ps32, n_seg, out, cs);
    } else {
        const int segs_per_block = 8;
        const int grid = (n_seg + segs_per_block - 1) / segs_per_block;
        jagged_fallback_kernel<<<grid, 256, 0, stream>>>(values, ps32, n_seg, out);
    }
}